// Round 7
// baseline (152.107 us; speedup 1.0000x reference)
//
#include <hip/hip_runtime.h>

// WeightedKappaLoss: kappa = 1 - (N * sum(W*conf)) / sum(W_ij * ht_i * hp_j)
// conf = 6x6 confusion histogram of (y_true, argmax(y_pred_row)).
// softmax is monotone -> argmax on raw logits. All counts exact integers;
// final ratio in double -> absmax == 0 vs reference (verified R0/R2/R4-R6).
//
// R7: R6's non-temporal loads were the first confirmed win (148.8 vs 153.3
// baseline; R4 LDS-stage 155.6, R5 MLP-4 157.5 both neutral): bypassing L3
// allocation avoids fighting the harness's fill-dirtied 256 MB L3.
// nt reads are served at HBM latency (~900 cyc) every time -> R6's 16
// waves/CU (GRID=1024) can't post enough in-flight bytes (Little's law).
// R7 = R6 loop UNCHANGED + GRID 1024->2048 (8 blocks/CU = full 32 waves/CU).
// Single-knob A/B on top of the confirmed win for clean attribution.
//   - direct stride-48 nt float4 loads (each 64B line fetched once; no
//     L3 allocate / no dirty-line eviction fights)
//   - per-wave LDS histograms (no inter-wave atomic serialization)
//   - race-free per-block 144 B partial store; small second kernel reduces
//     (R2 measured fused last-block fan-in at ~+95 us: 2048 same-address
//     device atomics + per-block __threadfence -- never again)
// Fills (2 x 384 MB poison @ ~85% peak = ~112 us) are harness-owned floor;
// controllable floor ~= 17.8 us count + ~5 us final/gaps => ~135 us total.

#define NC 6
#define NBINS 36
#define BLOCK 256
#define WPB (BLOCK / 64)            // 4 waves per block
#define GRID 2048                   // 8 blocks/CU -> full 32 waves/CU
#define SEGS 16
#define FIN_THREADS (NBINS * SEGS)  // 576 = 9 waves

typedef float f4 __attribute__((ext_vector_type(4)));

__global__ __launch_bounds__(BLOCK) void kappa_count(
    const f4* __restrict__ yp4, const unsigned long long* __restrict__ yt2,
    const float* __restrict__ yp, const int* __restrict__ yt,
    unsigned int* __restrict__ gconf, int npairs, int N) {
    __shared__ unsigned int sconf[WPB][NBINS];   // per-wave histograms
    const int tid = threadIdx.x;
    const int w = tid >> 6;
    if (tid < WPB * NBINS) ((unsigned int*)sconf)[tid] = 0u;
    __syncthreads();

    unsigned int* my = sconf[w];
    const int stride = GRID * BLOCK;

    for (int i = blockIdx.x * BLOCK + tid; i < npairs; i += stride) {
        // Non-temporal: read-through, no L3 allocation, no dirty-line fights.
        const f4 a = __builtin_nontemporal_load(&yp4[3 * i]);
        const f4 b = __builtin_nontemporal_load(&yp4[3 * i + 1]);
        const f4 d = __builtin_nontemporal_load(&yp4[3 * i + 2]);
        const unsigned long long tt = __builtin_nontemporal_load(&yt2[i]);
        const int t0 = (int)(tt & 0xffffffffull);
        const int t1 = (int)(tt >> 32);

        // row 0: a0 a1 a2 a3 b0 b1 (strict > keeps first max = jnp.argmax)
        float m = a.x; int p = 0;
        if (a.y > m) { m = a.y; p = 1; }
        if (a.z > m) { m = a.z; p = 2; }
        if (a.w > m) { m = a.w; p = 3; }
        if (b.x > m) { m = b.x; p = 4; }
        if (b.y > m) { m = b.y; p = 5; }
        atomicAdd(&my[t0 * NC + p], 1u);

        // row 1: b2 b3 d0 d1 d2 d3
        m = b.z; p = 0;
        if (b.w > m) { m = b.w; p = 1; }
        if (d.x > m) { m = d.x; p = 2; }
        if (d.y > m) { m = d.y; p = 3; }
        if (d.z > m) { m = d.z; p = 4; }
        if (d.w > m) { m = d.w; p = 5; }
        atomicAdd(&my[t1 * NC + p], 1u);
    }

    // odd-N tail row (N=4e6 is even; kept for generality)
    if ((N & 1) && blockIdx.x == 0 && tid == 0) {
        const int r = N - 1;
        float m = yp[r * NC]; int p = 0;
        #pragma unroll
        for (int j = 1; j < NC; ++j) {
            const float v = yp[r * NC + j];
            if (v > m) { m = v; p = j; }
        }
        atomicAdd(&my[yt[r] * NC + p], 1u);
    }

    __syncthreads();
    // Race-free per-block writedown: merge 4 wave histograms, one coalesced
    // 144 B store per block. No global atomics, no fences, no prior memset.
    if (tid < NBINS) {
        unsigned int s = 0;
        #pragma unroll
        for (int k = 0; k < WPB; ++k) s += sconf[k][tid];
        gconf[blockIdx.x * NBINS + tid] = s;
    }
}

__global__ void kappa_final_kernel(const unsigned int* __restrict__ gconf,
                                   float* __restrict__ out, long long N) {
    // 576 threads, each sums 128 of the 2048 partials for one bin (9 waves,
    // independent unrolled loads -> latency hidden).
    __shared__ unsigned int part[SEGS][NBINS];
    __shared__ unsigned int conf_s[NBINS];
    const int tid = threadIdx.x;
    if (tid < FIN_THREADS) {
        const int bin = tid % NBINS;
        const int seg = tid / NBINS;
        unsigned int s = 0;
        const int b0 = seg * (GRID / SEGS);
        #pragma unroll 8
        for (int b = b0; b < b0 + GRID / SEGS; ++b) s += gconf[b * NBINS + bin];
        part[seg][bin] = s;
    }
    __syncthreads();
    if (tid < NBINS) {
        unsigned int tot = 0;
        #pragma unroll
        for (int s2 = 0; s2 < SEGS; ++s2) tot += part[s2][tid];
        conf_s[tid] = tot;   // per-bin total <= N=4e6, exact in u32
    }
    __syncthreads();
    if (tid == 0) {
        long long conf[NBINS], ht[NC], hp[NC];
        #pragma unroll
        for (int i = 0; i < NC; ++i) { ht[i] = 0; hp[i] = 0; }
        #pragma unroll
        for (int k = 0; k < NBINS; ++k) conf[k] = (long long)conf_s[k];

        long long num = 0;
        #pragma unroll
        for (int i = 0; i < NC; ++i)
            #pragma unroll
            for (int j = 0; j < NC; ++j) {
                const long long w = (long long)(i - j) * (i - j);
                num += w * conf[i * NC + j];
                ht[i] += conf[i * NC + j];
                hp[j] += conf[i * NC + j];
            }
        long long den = 0;
        #pragma unroll
        for (int i = 0; i < NC; ++i)
            #pragma unroll
            for (int j = 0; j < NC; ++j)
                den += (long long)(i - j) * (i - j) * ht[i] * hp[j];

        out[0] = (float)(1.0 - ((double)num * (double)N) / (double)den);
    }
}

extern "C" void kernel_launch(void* const* d_in, const int* in_sizes, int n_in,
                              void* d_out, int out_size, void* d_ws, size_t ws_size,
                              hipStream_t stream) {
    const float* yp = (const float*)d_in[0];
    const int* yt = (const int*)d_in[1];   // int32 on device (verified: absmax=0)
    const int N = in_sizes[1];
    unsigned int* gconf = (unsigned int*)d_ws;  // GRID*NBINS uints = 288 KB

    const int npairs = N / 2;
    kappa_count<<<GRID, BLOCK, 0, stream>>>(
        (const f4*)yp, (const unsigned long long*)yt, yp, yt, gconf, npairs, N);
    kappa_final_kernel<<<1, FIN_THREADS, 0, stream>>>(gconf, (float*)d_out,
                                                      (long long)N);
}

// Round 8
// 143.960 us; speedup vs baseline: 1.0566x; 1.0566x over previous
//
#include <hip/hip_runtime.h>

// WeightedKappaLoss: kappa = 1 - (N * sum(W*conf)) / sum(W_ij * ht_i * hp_j)
// conf = 6x6 confusion histogram of (y_true, argmax(y_pred_row)).
// softmax is monotone -> argmax on raw logits. Counts exact; ratio in double
// -> absmax == 0 (verified R0/R2/R4-R7).
//
// R8 theory: harness's 384 MB poison fill dirties all 256 MB of L3 each
// iteration; our reads allocate in L3 and evict DIRTY fill lines -> ~112 MB
// of writebacks accompany our 112 MB of reads (224 MB fabric ~= 33 us ==
// observed count time). Occupancy (R7), MLP (R5), staging (R4) all neutral
// because none changes allocation policy. R6's nt (+4.5 us) was the L2-level
// hint only. R8 issues loads via inline asm with "sc1 nt" (device-scope,
// non-temporal: serviced past L2, no-retain) -- the closest ISA expression
// of pure streaming. Since sc1 bypasses L2, the stride-48 direct pattern
// would over-fetch 3x -> use the R4 coalesced-load + LDS-bounce shape
// (each 64B line touched by exactly one instruction), which R4 proved
// correctness-safe (__threadfence_block) and perf-free.
// Asm loads are not vmcnt-tracked by the compiler: explicit
// s_waitcnt vmcnt(0) + sched_barrier(0) before the ds_writes (rule #18).
// Cross-iteration LDS WAR (read(c) vs write(c+1)) is ordered by the
// asm-volatile memory clobbers (next loads + waitcnt) between them.
// Structure: GRID=1024 x BLOCK=256 (R6-proven best occupancy), per-wave
// LDS histograms, race-free 144 B per-block partial store, small final
// kernel (R2: fused last-block fan-in costs ~95 us -- never again).

#define NC 6
#define NBINS 36
#define BLOCK 256
#define WPB (BLOCK / 64)            // 4 waves per block
#define GRID 1024                   // 4 blocks/CU, 16 waves/CU (R6 config)
#define CHUNK 64                    // pairs per wave-iteration (3 KB logits)
#define SEGS 16
#define FIN_THREADS (NBINS * SEGS)  // 576 = 9 waves

typedef float f4 __attribute__((ext_vector_type(4)));

__device__ __forceinline__ f4 ld_stream_b128(const f4* p) {
    f4 r;
    asm volatile("global_load_dwordx4 %0, %1, off sc1 nt"
                 : "=v"(r) : "v"(p) : "memory");
    return r;
}
__device__ __forceinline__ unsigned long long ld_stream_b64(
    const unsigned long long* p) {
    unsigned long long r;
    asm volatile("global_load_dwordx2 %0, %1, off sc1 nt"
                 : "=v"(r) : "v"(p) : "memory");
    return r;
}

__global__ __launch_bounds__(BLOCK) void kappa_count(
    const f4* __restrict__ yp4, const unsigned long long* __restrict__ yt2,
    const float* __restrict__ yp, const int* __restrict__ yt,
    unsigned int* __restrict__ gconf, int npairs, int N) {
    __shared__ f4 stage[WPB][3 * CHUNK];          // 12 KB, wave-private rows
    __shared__ unsigned int sconf[WPB][NBINS];    // per-wave histograms
    const int tid = threadIdx.x;
    const int w = tid >> 6;
    const int L = tid & 63;
    if (tid < WPB * NBINS) ((unsigned int*)sconf)[tid] = 0u;
    __syncthreads();

    unsigned int* my = sconf[w];
    f4* st = stage[w];

    const int nchunks = npairs / CHUNK;
    const int gwaves = GRID * WPB;                // 4096 waves in grid
    for (int c = blockIdx.x * WPB + w; c < nchunks; c += gwaves) {
        // Coalesced streaming loads: each 64 B line touched by exactly one
        // instruction (sc1 bypasses L2 -> over-fetch would be fatal here).
        const f4 g0 = ld_stream_b128(&yp4[c * 3 * CHUNK + L]);
        const f4 g1 = ld_stream_b128(&yp4[c * 3 * CHUNK + 64 + L]);
        const f4 g2 = ld_stream_b128(&yp4[c * 3 * CHUNK + 128 + L]);
        const unsigned long long tt = ld_stream_b64(&yt2[c * CHUNK + L]);
        // Asm loads are not compiler-tracked: drain vmcnt before LDS writes,
        // and pin the schedule (rule #18).
        asm volatile("s_waitcnt vmcnt(0)" ::: "memory");
        __builtin_amdgcn_sched_barrier(0);
        st[L] = g0;
        st[64 + L] = g1;
        st[128 + L] = g2;
        // Cross-lane exchange through LDS: fence REQUIRED (R3 post-mortem);
        // orders ds_write before ds_read at IR level + waits lgkmcnt(0).
        __threadfence_block();
        const f4 a = st[3 * L];
        const f4 b = st[3 * L + 1];
        const f4 d = st[3 * L + 2];
        const int t0 = (int)(tt & 0xffffffffull);
        const int t1 = (int)(tt >> 32);

        // row 0: a0 a1 a2 a3 b0 b1 (strict > keeps first max = jnp.argmax)
        float m = a.x; int p = 0;
        if (a.y > m) { m = a.y; p = 1; }
        if (a.z > m) { m = a.z; p = 2; }
        if (a.w > m) { m = a.w; p = 3; }
        if (b.x > m) { m = b.x; p = 4; }
        if (b.y > m) { m = b.y; p = 5; }
        atomicAdd(&my[t0 * NC + p], 1u);

        // row 1: b2 b3 d0 d1 d2 d3
        m = b.z; p = 0;
        if (b.w > m) { m = b.w; p = 1; }
        if (d.x > m) { m = d.x; p = 2; }
        if (d.y > m) { m = d.y; p = 3; }
        if (d.z > m) { m = d.z; p = 4; }
        if (d.w > m) { m = d.w; p = 5; }
        atomicAdd(&my[t1 * NC + p], 1u);
    }

    // leftover pairs (npairs % 64; zero for N=4e6) — plain direct loads
    const int rem0 = nchunks * CHUNK;
    if (blockIdx.x == 0 && tid < npairs - rem0) {
        const int i = rem0 + tid;
        const f4 a = yp4[3 * i];
        const f4 b = yp4[3 * i + 1];
        const f4 d = yp4[3 * i + 2];
        const unsigned long long tt = yt2[i];
        const int t0 = (int)(tt & 0xffffffffull);
        const int t1 = (int)(tt >> 32);
        float m = a.x; int p = 0;
        if (a.y > m) { m = a.y; p = 1; }
        if (a.z > m) { m = a.z; p = 2; }
        if (a.w > m) { m = a.w; p = 3; }
        if (b.x > m) { m = b.x; p = 4; }
        if (b.y > m) { m = b.y; p = 5; }
        atomicAdd(&my[t0 * NC + p], 1u);
        m = b.z; p = 0;
        if (b.w > m) { m = b.w; p = 1; }
        if (d.x > m) { m = d.x; p = 2; }
        if (d.y > m) { m = d.y; p = 3; }
        if (d.z > m) { m = d.z; p = 4; }
        if (d.w > m) { m = d.w; p = 5; }
        atomicAdd(&my[t1 * NC + p], 1u);
    }

    // odd-N tail row (N=4e6 is even; kept for generality)
    if ((N & 1) && blockIdx.x == 0 && tid == 0) {
        const int r = N - 1;
        float m = yp[r * NC]; int p = 0;
        #pragma unroll
        for (int j = 1; j < NC; ++j) {
            const float v = yp[r * NC + j];
            if (v > m) { m = v; p = j; }
        }
        atomicAdd(&my[yt[r] * NC + p], 1u);
    }

    __syncthreads();
    // Race-free per-block writedown: merge 4 wave histograms, one coalesced
    // 144 B store per block. No global atomics, no fences, no prior memset.
    // (Kernel-end implicit release flushes L2 -> final kernel sees it.)
    if (tid < NBINS) {
        unsigned int s = 0;
        #pragma unroll
        for (int k = 0; k < WPB; ++k) s += sconf[k][tid];
        gconf[blockIdx.x * NBINS + tid] = s;
    }
}

__global__ void kappa_final_kernel(const unsigned int* __restrict__ gconf,
                                   float* __restrict__ out, long long N) {
    // 576 threads, each sums 64 of the 1024 partials for one bin (9 waves,
    // independent unrolled loads -> latency hidden).
    __shared__ unsigned int part[SEGS][NBINS];
    __shared__ unsigned int conf_s[NBINS];
    const int tid = threadIdx.x;
    if (tid < FIN_THREADS) {
        const int bin = tid % NBINS;
        const int seg = tid / NBINS;
        unsigned int s = 0;
        const int b0 = seg * (GRID / SEGS);
        #pragma unroll 8
        for (int b = b0; b < b0 + GRID / SEGS; ++b) s += gconf[b * NBINS + bin];
        part[seg][bin] = s;
    }
    __syncthreads();
    if (tid < NBINS) {
        unsigned int tot = 0;
        #pragma unroll
        for (int s2 = 0; s2 < SEGS; ++s2) tot += part[s2][tid];
        conf_s[tid] = tot;   // per-bin total <= N=4e6, exact in u32
    }
    __syncthreads();
    if (tid == 0) {
        long long conf[NBINS], ht[NC], hp[NC];
        #pragma unroll
        for (int i = 0; i < NC; ++i) { ht[i] = 0; hp[i] = 0; }
        #pragma unroll
        for (int k = 0; k < NBINS; ++k) conf[k] = (long long)conf_s[k];

        long long num = 0;
        #pragma unroll
        for (int i = 0; i < NC; ++i)
            #pragma unroll
            for (int j = 0; j < NC; ++j) {
                const long long w = (long long)(i - j) * (i - j);
                num += w * conf[i * NC + j];
                ht[i] += conf[i * NC + j];
                hp[j] += conf[i * NC + j];
            }
        long long den = 0;
        #pragma unroll
        for (int i = 0; i < NC; ++i)
            #pragma unroll
            for (int j = 0; j < NC; ++j)
                den += (long long)(i - j) * (i - j) * ht[i] * hp[j];

        out[0] = (float)(1.0 - ((double)num * (double)N) / (double)den);
    }
}

extern "C" void kernel_launch(void* const* d_in, const int* in_sizes, int n_in,
                              void* d_out, int out_size, void* d_ws, size_t ws_size,
                              hipStream_t stream) {
    const float* yp = (const float*)d_in[0];
    const int* yt = (const int*)d_in[1];   // int32 on device (verified: absmax=0)
    const int N = in_sizes[1];
    unsigned int* gconf = (unsigned int*)d_ws;  // GRID*NBINS uints = 144 KB

    const int npairs = N / 2;
    kappa_count<<<GRID, BLOCK, 0, stream>>>(
        (const f4*)yp, (const unsigned long long*)yt, yp, yt, gconf, npairs, N);
    kappa_final_kernel<<<1, FIN_THREADS, 0, stream>>>(gconf, (float*)d_out,
                                                      (long long)N);
}